// Round 18
// baseline (315.974 us; speedup 1.0000x reference)
//
#include <hip/hip_runtime.h>

#define NN 100000
#define NE 1600000
#define DD 64
#define NB 196                             // coarse buckets (dst>>9)
#define BKT 512                            // nodes per bucket
#define CAP 9000                           // bucket capacity (mean 8192, +9 sigma)
#define NOCT 12500                         // NN / 8 nodes-per-wave (gemm)
#define NH 391                             // edge-pass blocks (4 int4/thread)
#define NG1 1024                           // self-GEMM blocks

// ---------------- init: bucket cursors at fixed segment bases ---------------
__global__ void init_kernel(int* __restrict__ gcursor) {
  int t = threadIdx.x;
  if (t < NB) gcursor[t] = t * CAP;
}

// ---------------- pass 1: scatter (src,dst) into fixed bucket segments ------
__launch_bounds__(256)
__global__ void scatter2_kernel(const int* __restrict__ src, const int* __restrict__ dst,
                                int* __restrict__ gcursor, int2* __restrict__ pairs) {
  __shared__ int lh[NB];
  __shared__ int lbase[NB];
  __shared__ int lcur[NB];
  const int NQ = NE / 4;
  int t = blockIdx.x * 256 + threadIdx.x;
  const int nt = NH * 256;
  for (int i = threadIdx.x; i < NB; i += 256) lh[i] = 0;
  __syncthreads();
  int4 dv[4], sv[4];
  bool pv[4];
  #pragma unroll
  for (int k = 0; k < 4; ++k) {
    int idx = t + k * nt;
    pv[k] = idx < NQ;
    if (pv[k]) {
      dv[k] = reinterpret_cast<const int4*>(dst)[idx];
      sv[k] = reinterpret_cast<const int4*>(src)[idx];
      atomicAdd(&lh[dv[k].x >> 9], 1);
      atomicAdd(&lh[dv[k].y >> 9], 1);
      atomicAdd(&lh[dv[k].z >> 9], 1);
      atomicAdd(&lh[dv[k].w >> 9], 1);
    }
  }
  __syncthreads();
  for (int i = threadIdx.x; i < NB; i += 256) {
    lcur[i] = 0;
    lbase[i] = lh[i] ? atomicAdd(&gcursor[i], lh[i]) : 0;
  }
  __syncthreads();
  #pragma unroll
  for (int k = 0; k < 4; ++k) {
    if (pv[k]) {
      int b;
      b = dv[k].x >> 9; pairs[lbase[b] + atomicAdd(&lcur[b], 1)] = make_int2(sv[k].x, dv[k].x);
      b = dv[k].y >> 9; pairs[lbase[b] + atomicAdd(&lcur[b], 1)] = make_int2(sv[k].y, dv[k].y);
      b = dv[k].z >> 9; pairs[lbase[b] + atomicAdd(&lcur[b], 1)] = make_int2(sv[k].z, dv[k].z);
      b = dv[k].w >> 9; pairs[lbase[b] + atomicAdd(&lcur[b], 1)] = make_int2(sv[k].w, dv[k].w);
    }
  }
}

// ---------------- pass 2: per-bucket exact CSR (all LDS) --------------------
__launch_bounds__(256)
__global__ void csr_kernel(const int2* __restrict__ pairs, const int* __restrict__ gcursor,
                           int* __restrict__ deg, int* __restrict__ off,
                           int* __restrict__ adj) {
  __shared__ int lh[BKT];
  __shared__ int wsum[4];
  int b = blockIdx.x;
  int t = threadIdx.x;
  int rs = b * CAP, re = gcursor[b];
  lh[2 * t] = 0;
  lh[2 * t + 1] = 0;
  __syncthreads();
  for (int i = rs + t; i < re; i += 256)
    atomicAdd(&lh[pairs[i].y - b * BKT], 1);
  __syncthreads();
  int lane = t & 63, w = t >> 6;
  int h0 = lh[2 * t], h1 = lh[2 * t + 1];
  int s = h0 + h1, incl = s;
  #pragma unroll
  for (int o = 1; o < 64; o <<= 1) {
    int u = __shfl_up(incl, o, 64);
    if (lane >= o) incl += u;
  }
  if (lane == 63) wsum[w] = incl;
  __syncthreads();
  int prefix = 0;
  for (int u = 0; u < w; ++u) prefix += wsum[u];
  int excl = prefix + incl - s;
  int n0 = b * BKT + 2 * t, n1 = n0 + 1;
  if (n0 < NN) { deg[n0] = h0; off[n0] = rs + excl; }
  if (n1 < NN) { deg[n1] = h1; off[n1] = rs + excl + h0; }
  lh[2 * t] = excl;
  lh[2 * t + 1] = excl + h0;
  __syncthreads();
  for (int i = rs + t; i < re; i += 256) {
    int2 e = pairs[i];
    int pos = atomicAdd(&lh[e.y - b * BKT], 1);
    adj[rs + pos] = e.x;
  }
}

// ---------------- layer1 self-GEMM || combine+pack --------------------------
// combine role also pre-packs w1r / w2l / w2r into global [q][j] float4
// tables (wave-uniform q, lane-coalesced j) for the downstream GEMMs.
__launch_bounds__(256)
__global__ void selfgemm_kernel(const float* __restrict__ x,
                                const float* __restrict__ wl,
                                const float* __restrict__ bl,
                                const float* __restrict__ br,
                                float* __restrict__ tmp,
                                const float* __restrict__ wp1, const float* __restrict__ bp1,
                                const float* __restrict__ wp2, const float* __restrict__ bp2,
                                const float* __restrict__ w1r,
                                const float* __restrict__ w2l,
                                const float* __restrict__ w2r,
                                float* __restrict__ wc4f, float* __restrict__ bc,
                                float* __restrict__ wr1g,
                                float* __restrict__ wl2g,
                                float* __restrict__ wr2g) {
  __shared__ float4 wA4[16 * 64] __attribute__((aligned(16)));   // [q][j] 16KB
  __shared__ float sp[4][8][DD] __attribute__((aligned(16)));    // 8KB
  int bid = blockIdx.x;
  if (bid < NG1) {
    int tid = threadIdx.x;
    int j = tid & 63;
    int w = tid >> 6;                      // 0..3
    float* wAf = (float*)wA4;
    for (int i = tid; i < DD * DD; i += 256) {
      int jj = i >> 6, k = i & 63;         // wA4[k>>2][jj] elem (k&3) = wl[jj][k]
      wAf[(((k >> 2) * 64) + jj) * 4 + (k & 3)] = wl[i];
    }
    float bias = bl[j] + br[j];
    __syncthreads();
    const int ngrp = 3125;                 // 100000 / (4 waves * 8 nodes)
    for (int grp = bid; grp < ngrp; grp += NG1) {
      int n0 = (grp * 4 + w) * 8;
      const float4* xg = reinterpret_cast<const float4*>(&x[(size_t)n0 * DD]);
      float4* spv = reinterpret_cast<float4*>(&sp[w][0][0]);
      spv[j] = xg[j];
      spv[j + 64] = xg[j + 64];
      float acc[8];
      #pragma unroll
      for (int i = 0; i < 8; ++i) acc[i] = bias;
      #pragma unroll
      for (int q = 0; q < 16; ++q) {
        int kb = q * 4;
        float4 wq = wA4[q * 64 + j];
        #pragma unroll
        for (int i = 0; i < 8; ++i) {
          float4 sv = *(const float4*)&sp[w][i][kb];   // LDS broadcast
          float a = acc[i];
          a = fmaf(sv.x, wq.x, a);
          a = fmaf(sv.y, wq.y, a);
          a = fmaf(sv.z, wq.z, a);
          a = fmaf(sv.w, wq.w, a);
          acc[i] = a;
        }
      }
      #pragma unroll
      for (int i = 0; i < 8; ++i) tmp[(size_t)(n0 + i) * DD + j] = acc[i];
    }
  } else {
    // combine (wc = wp2@wp1 folded, packed) + pack w1r/w2l/w2r
    int t = threadIdx.x;
    for (int idx = t; idx < DD * DD; idx += 256) {
      int jp = idx >> 6, k = idx & 63;     // jp wave-uniform, k = lane
      float s = 0.f;
      #pragma unroll
      for (int m = 0; m < DD; ++m) s = fmaf(wp2[jp * DD + m], wp1[m * DD + k], s);
      wc4f[(((k >> 2) * 64) + jp) * 4 + (k & 3)] = s;
      // pack: coalesced row reads, scattered 4B stores (cheap)
      wr1g[(((k >> 2) * 64) + jp) * 4 + (k & 3)] = w1r[idx];
      wl2g[(((k >> 2) * 64) + jp) * 4 + (k & 3)] = w2l[idx];
      wr2g[(((k >> 2) * 64) + jp) * 4 + (k & 3)] = w2r[idx];
    }
    if (t < DD) {
      float s = bp2[t];
      #pragma unroll
      for (int m = 0; m < DD; ++m) s = fmaf(wp2[t * DD + m], bp1[m], s);
      bc[t] = s;
    }
  }
}

// ---------------- gather-mean, 4 nodes/wave, float4 rows --------------------
__launch_bounds__(256)
__global__ void gather_kernel(const float* __restrict__ x,
                              const int* __restrict__ off,
                              const int* __restrict__ deg,
                              const int* __restrict__ adj,
                              float* __restrict__ prop) {
  const float4* X = reinterpret_cast<const float4*>(x);
  int wid = (blockIdx.x * 256 + threadIdx.x) >> 6;
  int nwaves = (gridDim.x * 256) >> 6;
  int lane = threadIdx.x & 63;
  int g = lane >> 4;
  int s = lane & 15;
  const int NQUAD = NN / 4;
  for (int q = wid; q < NQUAD; q += nwaves) {
    int n = q * 4 + g;
    int start = off[n];
    int d = deg[n];
    float4 a0 = {0,0,0,0}, a1 = {0,0,0,0}, a2 = {0,0,0,0}, a3 = {0,0,0,0};
    int t = 0;
    for (; t + 4 <= d; t += 4) {
      int i0 = adj[start + t + 0];
      int i1 = adj[start + t + 1];
      int i2 = adj[start + t + 2];
      int i3 = adj[start + t + 3];
      float4 v0 = X[i0 * 16 + s];
      float4 v1 = X[i1 * 16 + s];
      float4 v2 = X[i2 * 16 + s];
      float4 v3 = X[i3 * 16 + s];
      a0.x += v0.x; a0.y += v0.y; a0.z += v0.z; a0.w += v0.w;
      a1.x += v1.x; a1.y += v1.y; a1.z += v1.z; a1.w += v1.w;
      a2.x += v2.x; a2.y += v2.y; a2.z += v2.z; a2.w += v2.w;
      a3.x += v3.x; a3.y += v3.y; a3.z += v3.z; a3.w += v3.w;
    }
    if (t < d) {
      int dm = d - 1;
      int u1 = (t + 1 < d) ? t + 1 : dm;
      int u2 = (t + 2 < d) ? t + 2 : dm;
      int i0 = adj[start + t];
      int i1 = adj[start + u1];
      int i2 = adj[start + u2];
      float4 v0 = X[i0 * 16 + s];
      float4 v1 = X[i1 * 16 + s];
      float4 v2 = X[i2 * 16 + s];
      a0.x += v0.x; a0.y += v0.y; a0.z += v0.z; a0.w += v0.w;
      if (t + 1 < d) { a1.x += v1.x; a1.y += v1.y; a1.z += v1.z; a1.w += v1.w; }
      if (t + 2 < d) { a2.x += v2.x; a2.y += v2.y; a2.z += v2.z; a2.w += v2.w; }
    }
    float rc = 1.0f / fmaxf((float)d, 1.0f);
    float4 r;
    r.x = ((a0.x + a1.x) + (a2.x + a3.x)) * rc;
    r.y = ((a0.y + a1.y) + (a2.y + a3.y)) * rc;
    r.z = ((a0.z + a1.z) + (a2.z + a3.z)) * rc;
    r.w = ((a0.w + a1.w) + (a2.w + a3.w)) * rc;
    reinterpret_cast<float4*>(prop)[n * 16 + s] = r;
  }
}

// ---------------- light SAGE GEMM: out = relu(norm(tmp + prop@wr.T)) --------
// Weights from GLOBAL packed [q][j] float4 (wave-uniform q, lane-coalesced —
// L1/L2-hot, same pattern as wc4). LDS = pp only (16KB) -> high occupancy.
__launch_bounds__(512, 4)
__global__ void gemm_light_kernel(float* __restrict__ out,
                                  const float* __restrict__ prop,
                                  const float4* __restrict__ wr4) {
  __shared__ float pp[8][8][DD] __attribute__((aligned(16)));    // 16KB
  int tid = threadIdx.x;
  int j = tid & 63;
  int w = tid >> 6;

  const int ngrp = (NOCT + 7) / 8;   // 1563
  for (int grp = blockIdx.x; grp < ngrp; grp += gridDim.x) {
    int o = grp * 8 + w;
    if (o >= NOCT) continue;
    int n0 = o * 8;

    const float4* pg = reinterpret_cast<const float4*>(&prop[(size_t)n0 * DD]);
    float4* ppv = reinterpret_cast<float4*>(&pp[w][0][0]);
    ppv[j] = pg[j];
    ppv[j + 64] = pg[j + 64];

    float acc[8];
    #pragma unroll
    for (int i = 0; i < 8; ++i) acc[i] = out[(size_t)(n0 + i) * DD + j];  // tmp1

    #pragma unroll
    for (int q = 0; q < 16; ++q) {
      int kb = q * 4;
      float4 wq = wr4[q * 64 + j];                   // global, L1-hot
      #pragma unroll
      for (int i = 0; i < 8; ++i) {
        float4 pv = *(const float4*)&pp[w][i][kb];   // LDS broadcast
        float a = acc[i];
        a = fmaf(pv.x, wq.x, a);
        a = fmaf(pv.y, wq.y, a);
        a = fmaf(pv.z, wq.z, a);
        a = fmaf(pv.w, wq.w, a);
        acc[i] = a;
      }
    }

    #pragma unroll
    for (int i = 0; i < 8; ++i) {
      float a = acc[i];
      float ss = a * a;
      #pragma unroll
      for (int o2 = 32; o2 > 0; o2 >>= 1) ss += __shfl_xor(ss, o2, 64);
      float ov = a / fmaxf(sqrtf(ss), 1e-12f);
      ov = fmaxf(ov, 0.0f);
      out[(size_t)(n0 + i) * DD + j] = ov;
    }
  }
}

// ---------------- fused layer-2 SAGE GEMM + post-MLP ------------------------
// All weights (wl2/wr2/wc) from GLOBAL packed float4; LDS = sp+pp (32KB) ->
// up to full wave occupancy (was 64KB/2 blocks at R16).
__launch_bounds__(512, 4)
__global__ void sage_post_kernel(const float* __restrict__ xin,
                                 const float* __restrict__ prop,
                                 const float4* __restrict__ wl4,
                                 const float* __restrict__ bl,
                                 const float4* __restrict__ wr4,
                                 const float* __restrict__ br,
                                 const float4* __restrict__ wc4,
                                 const float* __restrict__ bc,
                                 float* __restrict__ out) {
  __shared__ float sp[8][8][DD] __attribute__((aligned(16)));    // 16KB
  __shared__ float pp[8][8][DD] __attribute__((aligned(16)));    // 16KB
  int tid = threadIdx.x;
  int j = tid & 63;
  int w = tid >> 6;

  float bias = bl[j] + br[j];
  float bcv = bc[j];

  const int ngrp = (NOCT + 7) / 8;
  for (int grp = blockIdx.x; grp < ngrp; grp += gridDim.x) {
    int o = grp * 8 + w;
    if (o >= NOCT) continue;
    int n0 = o * 8;

    const float4* xg = reinterpret_cast<const float4*>(&xin[(size_t)n0 * DD]);
    const float4* pg = reinterpret_cast<const float4*>(&prop[(size_t)n0 * DD]);
    float4* spv = reinterpret_cast<float4*>(&sp[w][0][0]);
    float4* ppv = reinterpret_cast<float4*>(&pp[w][0][0]);
    spv[j] = xg[j];
    spv[j + 64] = xg[j + 64];
    ppv[j] = pg[j];
    ppv[j + 64] = pg[j + 64];

    float acc[8];
    #pragma unroll
    for (int i = 0; i < 8; ++i) acc[i] = bias;

    #pragma unroll
    for (int q = 0; q < 16; ++q) {
      int kb = q * 4;
      float4 wlq = wl4[q * 64 + j];                  // global, L1/L2-hot
      float4 wrq = wr4[q * 64 + j];
      #pragma unroll
      for (int i = 0; i < 8; ++i) {
        float4 sv = *(const float4*)&sp[w][i][kb];   // LDS broadcast
        float4 pv = *(const float4*)&pp[w][i][kb];   // LDS broadcast
        float a = acc[i];
        a = fmaf(sv.x, wlq.x, a);
        a = fmaf(sv.y, wlq.y, a);
        a = fmaf(sv.z, wlq.z, a);
        a = fmaf(sv.w, wlq.w, a);
        a = fmaf(pv.x, wrq.x, a);
        a = fmaf(pv.y, wrq.y, a);
        a = fmaf(pv.z, wrq.z, a);
        a = fmaf(pv.w, wrq.w, a);
        acc[i] = a;
      }
    }

    // L2 normalize + relu -> stage h into sp (wave-local reuse)
    #pragma unroll
    for (int i = 0; i < 8; ++i) {
      float a = acc[i];
      float ss = a * a;
      #pragma unroll
      for (int o2 = 32; o2 > 0; o2 >>= 1) ss += __shfl_xor(ss, o2, 64);
      float ov = a / fmaxf(sqrtf(ss), 1e-12f);
      ov = fmaxf(ov, 0.0f);
      sp[w][i][j] = ov;
    }

    // post phase: out = h @ wc.T + bc
    float acc2[8];
    #pragma unroll
    for (int i = 0; i < 8; ++i) acc2[i] = bcv;
    #pragma unroll
    for (int q = 0; q < 16; ++q) {
      int kb = q * 4;
      float4 wq = wc4[q * 64 + j];
      #pragma unroll
      for (int i = 0; i < 8; ++i) {
        float4 hv = *(const float4*)&sp[w][i][kb];   // LDS broadcast
        float a = acc2[i];
        a = fmaf(hv.x, wq.x, a);
        a = fmaf(hv.y, wq.y, a);
        a = fmaf(hv.z, wq.z, a);
        a = fmaf(hv.w, wq.w, a);
        acc2[i] = a;
      }
    }
    #pragma unroll
    for (int i = 0; i < 8; ++i) out[(size_t)(n0 + i) * DD + j] = acc2[i];
  }
}

extern "C" void kernel_launch(void* const* d_in, const int* in_sizes, int n_in,
                              void* d_out, int out_size, void* d_ws, size_t ws_size,
                              hipStream_t stream) {
  const float* x   = (const float*)d_in[0];
  const int*   ei  = (const int*)d_in[1];
  const float* w1l = (const float*)d_in[2];
  const float* b1l = (const float*)d_in[3];
  const float* w1r = (const float*)d_in[4];
  const float* b1r = (const float*)d_in[5];
  const float* w2l = (const float*)d_in[6];
  const float* b2l = (const float*)d_in[7];
  const float* w2r = (const float*)d_in[8];
  const float* b2r = (const float*)d_in[9];
  const float* wp1 = (const float*)d_in[10];
  const float* bp1 = (const float*)d_in[11];
  const float* wp2 = (const float*)d_in[12];
  const float* bp2 = (const float*)d_in[13];
  float* out = (float*)d_out;

  const int* src = ei;
  const int* dst = ei + NE;

  // ws (4B units): deg[102400] | off[102400] | aux[1024] | wc4[4096] | bc[1024]
  //               | wr1g[4096] | wl2g[4096] | wr2g[4096]
  //               | adj[NB*CAP = 1764000] | prop[NN*DD]
  // pairs (int2[NB*CAP] = 14.1MB) aliases prop (dead before gather writes it).
  int* deg     = (int*)d_ws;
  int* off     = deg + 102400;
  int* aux     = off + 102400;
  int* gcursor = aux;
  float* wc4f  = (float*)(aux + 1024);
  float* bc    = wc4f + 4096;
  float* wr1g  = bc + 1024;
  float* wl2g  = wr1g + 4096;
  float* wr2g  = wl2g + 4096;
  int* adj     = (int*)(wr2g + 4096);
  float* prop  = (float*)(adj + NB * CAP);
  int2* pairs  = (int2*)prop;

  // ---- CSR build via fixed-capacity bucket sort (no per-edge global atomics)
  init_kernel<<<1, 256, 0, stream>>>(gcursor);
  scatter2_kernel<<<NH, 256, 0, stream>>>(src, dst, gcursor, pairs);
  csr_kernel<<<NB, 256, 0, stream>>>(pairs, gcursor, deg, off, adj);

  // ---- layer-1 self-GEMM (tmp1 -> out) + combine/pack (wc4, bc, w*g) ----
  selfgemm_kernel<<<NG1 + 1, 256, 0, stream>>>(x, w1l, b1l, b1r, out,
                                               wp1, bp1, wp2, bp2,
                                               w1r, w2l, w2r,
                                               wc4f, bc, wr1g, wl2g, wr2g);

  // ---- layer 1: gather(x)->prop; out = relu(norm(tmp1 + prop@w1r.T)) ----
  gather_kernel<<<2048, 256, 0, stream>>>(x, off, deg, adj, prop);
  gemm_light_kernel<<<1024, 512, 0, stream>>>(out, prop, (const float4*)wr1g);

  // ---- layer 2 + fused post: gather(out)->prop; sage+post -> out ----
  gather_kernel<<<2048, 256, 0, stream>>>(out, off, deg, adj, prop);
  sage_post_kernel<<<1024, 512, 0, stream>>>(out, prop,
                                             (const float4*)wl2g, b2l,
                                             (const float4*)wr2g, b2r,
                                             (const float4*)wc4f, bc, out);
}

// Round 19
// 275.435 us; speedup vs baseline: 1.1472x; 1.1472x over previous
//
#include <hip/hip_runtime.h>

#define NN 100000
#define NE 1600000
#define DD 64
#define NB 196                             // coarse buckets (dst>>9)
#define BKT 512                            // nodes per bucket
#define CAP 9000                           // bucket capacity (mean 8192, +9 sigma)
#define NOCT 12500                         // NN / 8 nodes-per-wave (gemm)
#define NH 391                             // edge-pass blocks (4 int4/thread)
#define NG1 1024                           // self-GEMM blocks

// ---------------- pass 1: scatter (src,dst) into fixed bucket segments ------
// gcursor zero-initialized by hipMemsetAsync; bucket base b*CAP is implicit.
__launch_bounds__(256)
__global__ void scatter2_kernel(const int* __restrict__ src, const int* __restrict__ dst,
                                int* __restrict__ gcursor, int2* __restrict__ pairs) {
  __shared__ int lh[NB];
  __shared__ int lbase[NB];
  __shared__ int lcur[NB];
  const int NQ = NE / 4;
  int t = blockIdx.x * 256 + threadIdx.x;
  const int nt = NH * 256;
  for (int i = threadIdx.x; i < NB; i += 256) lh[i] = 0;
  __syncthreads();
  int4 dv[4], sv[4];
  bool pv[4];
  #pragma unroll
  for (int k = 0; k < 4; ++k) {
    int idx = t + k * nt;
    pv[k] = idx < NQ;
    if (pv[k]) {
      dv[k] = reinterpret_cast<const int4*>(dst)[idx];
      sv[k] = reinterpret_cast<const int4*>(src)[idx];
      atomicAdd(&lh[dv[k].x >> 9], 1);
      atomicAdd(&lh[dv[k].y >> 9], 1);
      atomicAdd(&lh[dv[k].z >> 9], 1);
      atomicAdd(&lh[dv[k].w >> 9], 1);
    }
  }
  __syncthreads();
  for (int i = threadIdx.x; i < NB; i += 256) {
    lcur[i] = 0;
    lbase[i] = lh[i] ? (i * CAP + atomicAdd(&gcursor[i], lh[i])) : 0;
  }
  __syncthreads();
  #pragma unroll
  for (int k = 0; k < 4; ++k) {
    if (pv[k]) {
      int b;
      b = dv[k].x >> 9; pairs[lbase[b] + atomicAdd(&lcur[b], 1)] = make_int2(sv[k].x, dv[k].x);
      b = dv[k].y >> 9; pairs[lbase[b] + atomicAdd(&lcur[b], 1)] = make_int2(sv[k].y, dv[k].y);
      b = dv[k].z >> 9; pairs[lbase[b] + atomicAdd(&lcur[b], 1)] = make_int2(sv[k].z, dv[k].z);
      b = dv[k].w >> 9; pairs[lbase[b] + atomicAdd(&lcur[b], 1)] = make_int2(sv[k].w, dv[k].w);
    }
  }
}

// ---------------- pass 2: per-bucket exact CSR (all LDS) --------------------
__launch_bounds__(256)
__global__ void csr_kernel(const int2* __restrict__ pairs, const int* __restrict__ gcursor,
                           int* __restrict__ deg, int* __restrict__ off,
                           int* __restrict__ adj) {
  __shared__ int lh[BKT];
  __shared__ int wsum[4];
  int b = blockIdx.x;
  int t = threadIdx.x;
  int rs = b * CAP, re = rs + gcursor[b];
  lh[2 * t] = 0;
  lh[2 * t + 1] = 0;
  __syncthreads();
  for (int i = rs + t; i < re; i += 256)
    atomicAdd(&lh[pairs[i].y - b * BKT], 1);
  __syncthreads();
  int lane = t & 63, w = t >> 6;
  int h0 = lh[2 * t], h1 = lh[2 * t + 1];
  int s = h0 + h1, incl = s;
  #pragma unroll
  for (int o = 1; o < 64; o <<= 1) {
    int u = __shfl_up(incl, o, 64);
    if (lane >= o) incl += u;
  }
  if (lane == 63) wsum[w] = incl;
  __syncthreads();
  int prefix = 0;
  for (int u = 0; u < w; ++u) prefix += wsum[u];
  int excl = prefix + incl - s;
  int n0 = b * BKT + 2 * t, n1 = n0 + 1;
  if (n0 < NN) { deg[n0] = h0; off[n0] = rs + excl; }
  if (n1 < NN) { deg[n1] = h1; off[n1] = rs + excl + h0; }
  lh[2 * t] = excl;
  lh[2 * t + 1] = excl + h0;
  __syncthreads();
  for (int i = rs + t; i < re; i += 256) {
    int2 e = pairs[i];
    int pos = atomicAdd(&lh[e.y - b * BKT], 1);
    adj[rs + pos] = e.x;
  }
}

// ---------------- layer1 self-GEMM (tmp1 = x@w1l.T + b1l+b1r) || combine ----
__launch_bounds__(256)
__global__ void selfgemm_kernel(const float* __restrict__ x,
                                const float* __restrict__ wl,
                                const float* __restrict__ bl,
                                const float* __restrict__ br,
                                float* __restrict__ tmp,
                                const float* __restrict__ wp1, const float* __restrict__ bp1,
                                const float* __restrict__ wp2, const float* __restrict__ bp2,
                                float* __restrict__ wc4f, float* __restrict__ bc) {
  __shared__ float4 wA4[16 * 64] __attribute__((aligned(16)));   // [q][j] 16KB
  __shared__ float sp[4][8][DD] __attribute__((aligned(16)));    // 8KB
  int bid = blockIdx.x;
  if (bid < NG1) {
    int tid = threadIdx.x;
    int j = tid & 63;
    int w = tid >> 6;                      // 0..3
    float* wAf = (float*)wA4;
    for (int i = tid; i < DD * DD; i += 256) {
      int jj = i >> 6, k = i & 63;         // wA4[k>>2][jj] elem (k&3) = wl[jj][k]
      wAf[(((k >> 2) * 64) + jj) * 4 + (k & 3)] = wl[i];
    }
    float bias = bl[j] + br[j];
    __syncthreads();
    const int ngrp = 3125;                 // 100000 / (4 waves * 8 nodes)
    for (int grp = bid; grp < ngrp; grp += NG1) {
      int n0 = (grp * 4 + w) * 8;
      const float4* xg = reinterpret_cast<const float4*>(&x[(size_t)n0 * DD]);
      float4* spv = reinterpret_cast<float4*>(&sp[w][0][0]);
      spv[j] = xg[j];
      spv[j + 64] = xg[j + 64];
      float acc[8];
      #pragma unroll
      for (int i = 0; i < 8; ++i) acc[i] = bias;
      #pragma unroll
      for (int q = 0; q < 16; ++q) {
        int kb = q * 4;
        float4 wq = wA4[q * 64 + j];
        #pragma unroll
        for (int i = 0; i < 8; ++i) {
          float4 sv = *(const float4*)&sp[w][i][kb];   // LDS broadcast
          float a = acc[i];
          a = fmaf(sv.x, wq.x, a);
          a = fmaf(sv.y, wq.y, a);
          a = fmaf(sv.z, wq.z, a);
          a = fmaf(sv.w, wq.w, a);
          acc[i] = a;
        }
      }
      #pragma unroll
      for (int i = 0; i < 8; ++i) tmp[(size_t)(n0 + i) * DD + j] = acc[i];
    }
  } else {
    int t = threadIdx.x;
    for (int idx = t; idx < DD * DD; idx += 256) {
      int jp = idx >> 6, k = idx & 63;     // jp wave-uniform, k = lane
      float s = 0.f;
      #pragma unroll
      for (int m = 0; m < DD; ++m) s = fmaf(wp2[jp * DD + m], wp1[m * DD + k], s);
      wc4f[(((k >> 2) * 64) + jp) * 4 + (k & 3)] = s;  // packed [q][jp] store
    }
    if (t < DD) {
      float s = bp2[t];
      #pragma unroll
      for (int m = 0; m < DD; ++m) s = fmaf(wp2[t * DD + m], bp1[m], s);
      bc[t] = s;
    }
  }
}

// ---------------- gather-mean, 4 nodes/wave, float4 rows --------------------
__launch_bounds__(256)
__global__ void gather_kernel(const float* __restrict__ x,
                              const int* __restrict__ off,
                              const int* __restrict__ deg,
                              const int* __restrict__ adj,
                              float* __restrict__ prop) {
  const float4* X = reinterpret_cast<const float4*>(x);
  int wid = (blockIdx.x * 256 + threadIdx.x) >> 6;
  int nwaves = (gridDim.x * 256) >> 6;
  int lane = threadIdx.x & 63;
  int g = lane >> 4;
  int s = lane & 15;
  const int NQUAD = NN / 4;
  for (int q = wid; q < NQUAD; q += nwaves) {
    int n = q * 4 + g;
    int start = off[n];
    int d = deg[n];
    float4 a0 = {0,0,0,0}, a1 = {0,0,0,0}, a2 = {0,0,0,0}, a3 = {0,0,0,0};
    int t = 0;
    for (; t + 4 <= d; t += 4) {
      int i0 = adj[start + t + 0];
      int i1 = adj[start + t + 1];
      int i2 = adj[start + t + 2];
      int i3 = adj[start + t + 3];
      float4 v0 = X[i0 * 16 + s];
      float4 v1 = X[i1 * 16 + s];
      float4 v2 = X[i2 * 16 + s];
      float4 v3 = X[i3 * 16 + s];
      a0.x += v0.x; a0.y += v0.y; a0.z += v0.z; a0.w += v0.w;
      a1.x += v1.x; a1.y += v1.y; a1.z += v1.z; a1.w += v1.w;
      a2.x += v2.x; a2.y += v2.y; a2.z += v2.z; a2.w += v2.w;
      a3.x += v3.x; a3.y += v3.y; a3.z += v3.z; a3.w += v3.w;
    }
    if (t < d) {
      int dm = d - 1;
      int u1 = (t + 1 < d) ? t + 1 : dm;
      int u2 = (t + 2 < d) ? t + 2 : dm;
      int i0 = adj[start + t];
      int i1 = adj[start + u1];
      int i2 = adj[start + u2];
      float4 v0 = X[i0 * 16 + s];
      float4 v1 = X[i1 * 16 + s];
      float4 v2 = X[i2 * 16 + s];
      a0.x += v0.x; a0.y += v0.y; a0.z += v0.z; a0.w += v0.w;
      if (t + 1 < d) { a1.x += v1.x; a1.y += v1.y; a1.z += v1.z; a1.w += v1.w; }
      if (t + 2 < d) { a2.x += v2.x; a2.y += v2.y; a2.z += v2.z; a2.w += v2.w; }
    }
    float rc = 1.0f / fmaxf((float)d, 1.0f);
    float4 r;
    r.x = ((a0.x + a1.x) + (a2.x + a3.x)) * rc;
    r.y = ((a0.y + a1.y) + (a2.y + a3.y)) * rc;
    r.z = ((a0.z + a1.z) + (a2.z + a3.z)) * rc;
    r.w = ((a0.w + a1.w) + (a2.w + a3.w)) * rc;
    reinterpret_cast<float4*>(prop)[n * 16 + s] = r;
  }
}

// ---------------- light SAGE GEMM: out = relu(norm(tmp + prop@wr.T)) --------
__launch_bounds__(512, 4)
__global__ void gemm_light_kernel(float* __restrict__ out,
                                  const float* __restrict__ prop,
                                  const float* __restrict__ wr) {
  __shared__ float4 wrA4[16 * 64] __attribute__((aligned(16)));  // [q][j] 16KB
  __shared__ float pp[8][8][DD] __attribute__((aligned(16)));    // 16KB
  int tid = threadIdx.x;
  int j = tid & 63;
  int w = tid >> 6;
  float* wrf = (float*)wrA4;
  for (int i = tid; i < DD * DD; i += 512) {
    int jj = i >> 6, k = i & 63;
    wrf[(((k >> 2) * 64) + jj) * 4 + (k & 3)] = wr[i];
  }
  __syncthreads();

  const int ngrp = (NOCT + 7) / 8;   // 1563
  for (int grp = blockIdx.x; grp < ngrp; grp += gridDim.x) {
    int o = grp * 8 + w;
    if (o >= NOCT) continue;
    int n0 = o * 8;

    const float4* pg = reinterpret_cast<const float4*>(&prop[(size_t)n0 * DD]);
    float4* ppv = reinterpret_cast<float4*>(&pp[w][0][0]);
    ppv[j] = pg[j];
    ppv[j + 64] = pg[j + 64];

    float acc[8];
    #pragma unroll
    for (int i = 0; i < 8; ++i) acc[i] = out[(size_t)(n0 + i) * DD + j];  // tmp1

    #pragma unroll
    for (int q = 0; q < 16; ++q) {
      int kb = q * 4;
      float4 wq = wrA4[q * 64 + j];
      #pragma unroll
      for (int i = 0; i < 8; ++i) {
        float4 pv = *(const float4*)&pp[w][i][kb];   // LDS broadcast
        float a = acc[i];
        a = fmaf(pv.x, wq.x, a);
        a = fmaf(pv.y, wq.y, a);
        a = fmaf(pv.z, wq.z, a);
        a = fmaf(pv.w, wq.w, a);
        acc[i] = a;
      }
    }

    #pragma unroll
    for (int i = 0; i < 8; ++i) {
      float a = acc[i];
      float ss = a * a;
      #pragma unroll
      for (int o2 = 32; o2 > 0; o2 >>= 1) ss += __shfl_xor(ss, o2, 64);
      float ov = a / fmaxf(sqrtf(ss), 1e-12f);
      ov = fmaxf(ov, 0.0f);
      out[(size_t)(n0 + i) * DD + j] = ov;
    }
  }
}

// ---------------- fused layer-2 SAGE GEMM + post-MLP ------------------------
__launch_bounds__(512, 4)
__global__ void sage_post_kernel(const float* __restrict__ xin,
                                 const float* __restrict__ prop,
                                 const float* __restrict__ wl,
                                 const float* __restrict__ bl,
                                 const float* __restrict__ wr,
                                 const float* __restrict__ br,
                                 const float4* __restrict__ wc4,
                                 const float* __restrict__ bc,
                                 float* __restrict__ out) {
  __shared__ float4 wlA4[16 * 64] __attribute__((aligned(16)));  // 16KB
  __shared__ float4 wrA4[16 * 64] __attribute__((aligned(16)));  // 16KB
  __shared__ float sp[8][8][DD] __attribute__((aligned(16)));    // 16KB
  __shared__ float pp[8][8][DD] __attribute__((aligned(16)));    // 16KB
  int tid = threadIdx.x;
  int j = tid & 63;
  int w = tid >> 6;

  float* wlf = (float*)wlA4;
  float* wrf = (float*)wrA4;
  for (int i = tid; i < DD * DD; i += 512) {
    int jj = i >> 6, k = i & 63;
    wlf[(((k >> 2) * 64) + jj) * 4 + (k & 3)] = wl[i];
    wrf[(((k >> 2) * 64) + jj) * 4 + (k & 3)] = wr[i];
  }
  float bias = bl[j] + br[j];
  float bcv = bc[j];
  __syncthreads();

  const int ngrp = (NOCT + 7) / 8;
  for (int grp = blockIdx.x; grp < ngrp; grp += gridDim.x) {
    int o = grp * 8 + w;
    if (o >= NOCT) continue;
    int n0 = o * 8;

    const float4* xg = reinterpret_cast<const float4*>(&xin[(size_t)n0 * DD]);
    const float4* pg = reinterpret_cast<const float4*>(&prop[(size_t)n0 * DD]);
    float4* spv = reinterpret_cast<float4*>(&sp[w][0][0]);
    float4* ppv = reinterpret_cast<float4*>(&pp[w][0][0]);
    spv[j] = xg[j];
    spv[j + 64] = xg[j + 64];
    ppv[j] = pg[j];
    ppv[j + 64] = pg[j + 64];

    float acc[8];
    #pragma unroll
    for (int i = 0; i < 8; ++i) acc[i] = bias;

    #pragma unroll
    for (int q = 0; q < 16; ++q) {
      int kb = q * 4;
      float4 wlq = wlA4[q * 64 + j];
      float4 wrq = wrA4[q * 64 + j];
      #pragma unroll
      for (int i = 0; i < 8; ++i) {
        float4 sv = *(const float4*)&sp[w][i][kb];   // LDS broadcast
        float4 pv = *(const float4*)&pp[w][i][kb];   // LDS broadcast
        float a = acc[i];
        a = fmaf(sv.x, wlq.x, a);
        a = fmaf(sv.y, wlq.y, a);
        a = fmaf(sv.z, wlq.z, a);
        a = fmaf(sv.w, wlq.w, a);
        a = fmaf(pv.x, wrq.x, a);
        a = fmaf(pv.y, wrq.y, a);
        a = fmaf(pv.z, wrq.z, a);
        a = fmaf(pv.w, wrq.w, a);
        acc[i] = a;
      }
    }

    // L2 normalize + relu -> stage h into sp (wave-local reuse)
    #pragma unroll
    for (int i = 0; i < 8; ++i) {
      float a = acc[i];
      float ss = a * a;
      #pragma unroll
      for (int o2 = 32; o2 > 0; o2 >>= 1) ss += __shfl_xor(ss, o2, 64);
      float ov = a / fmaxf(sqrtf(ss), 1e-12f);
      ov = fmaxf(ov, 0.0f);
      sp[w][i][j] = ov;
    }

    // post phase: out = h @ wc.T + bc ; wc4 from global (coalesced, L1-hot)
    float acc2[8];
    #pragma unroll
    for (int i = 0; i < 8; ++i) acc2[i] = bcv;
    #pragma unroll
    for (int q = 0; q < 16; ++q) {
      int kb = q * 4;
      float4 wq = wc4[q * 64 + j];
      #pragma unroll
      for (int i = 0; i < 8; ++i) {
        float4 hv = *(const float4*)&sp[w][i][kb];   // LDS broadcast
        float a = acc2[i];
        a = fmaf(hv.x, wq.x, a);
        a = fmaf(hv.y, wq.y, a);
        a = fmaf(hv.z, wq.z, a);
        a = fmaf(hv.w, wq.w, a);
        acc2[i] = a;
      }
    }
    #pragma unroll
    for (int i = 0; i < 8; ++i) out[(size_t)(n0 + i) * DD + j] = acc2[i];
  }
}

extern "C" void kernel_launch(void* const* d_in, const int* in_sizes, int n_in,
                              void* d_out, int out_size, void* d_ws, size_t ws_size,
                              hipStream_t stream) {
  const float* x   = (const float*)d_in[0];
  const int*   ei  = (const int*)d_in[1];
  const float* w1l = (const float*)d_in[2];
  const float* b1l = (const float*)d_in[3];
  const float* w1r = (const float*)d_in[4];
  const float* b1r = (const float*)d_in[5];
  const float* w2l = (const float*)d_in[6];
  const float* b2l = (const float*)d_in[7];
  const float* w2r = (const float*)d_in[8];
  const float* b2r = (const float*)d_in[9];
  const float* wp1 = (const float*)d_in[10];
  const float* bp1 = (const float*)d_in[11];
  const float* wp2 = (const float*)d_in[12];
  const float* bp2 = (const float*)d_in[13];
  float* out = (float*)d_out;

  const int* src = ei;
  const int* dst = ei + NE;

  // ws (4B units): deg[102400] | off[102400] | aux[1024] | wc4[4096] | bc[1024]
  //               | adj[NB*CAP = 1764000] | prop[NN*DD]
  // pairs (int2[NB*CAP] = 14.1MB) aliases prop (dead before gather writes it).
  int* deg     = (int*)d_ws;
  int* off     = deg + 102400;
  int* aux     = off + 102400;
  int* gcursor = aux;
  float* wc4f  = (float*)(aux + 1024);
  float* bc    = wc4f + 4096;
  int* adj     = (int*)(bc + 1024);
  float* prop  = (float*)(adj + NB * CAP);
  int2* pairs  = (int2*)prop;

  // ---- CSR build via fixed-capacity bucket sort (no per-edge global atomics)
  hipMemsetAsync(gcursor, 0, NB * sizeof(int), stream);
  scatter2_kernel<<<NH, 256, 0, stream>>>(src, dst, gcursor, pairs);
  csr_kernel<<<NB, 256, 0, stream>>>(pairs, gcursor, deg, off, adj);

  // ---- layer-1 self-GEMM (tmp1 -> out) + post-weight folding (wc4, bc) ----
  selfgemm_kernel<<<NG1 + 1, 256, 0, stream>>>(x, w1l, b1l, b1r, out,
                                               wp1, bp1, wp2, bp2, wc4f, bc);

  // ---- layer 1: gather(x)->prop; out = relu(norm(tmp1 + prop@w1r.T)) ----
  gather_kernel<<<2048, 256, 0, stream>>>(x, off, deg, adj, prop);
  gemm_light_kernel<<<1024, 512, 0, stream>>>(out, prop, w1r);

  // ---- layer 2 + fused post: gather(out)->prop; sage+post -> out ----
  gather_kernel<<<2048, 256, 0, stream>>>(out, off, deg, adj, prop);
  sage_post_kernel<<<512, 512, 0, stream>>>(out, prop, w2l, b2l, w2r, b2r,
                                            (const float4*)wc4f, bc, out);
}

// Round 20
// 266.484 us; speedup vs baseline: 1.1857x; 1.0336x over previous
//
#include <hip/hip_runtime.h>

#define NN 100000
#define NE 1600000
#define DD 64
#define NB 196                             // coarse buckets (dst>>9)
#define BKT 512                            // nodes per bucket
#define CAP 9000                           // bucket capacity (mean 8192, +9 sigma)
#define NOCT 12500                         // NN / 8 nodes-per-wave (gemm)
#define NH 391                             // edge-pass blocks (4 int4/thread)
#define NG1 1024                           // self-GEMM blocks

// ---------------- mega: scatter2 (edges->buckets)  ||  selfgemm  ||  combine
// Roles are independent (edges vs x@w1l) and use disjoint pipes
// (VMEM/LDS-atomics vs VALU/DS). LDS is a UNION (R8 lesson: __shared__
// declarations SUM) -- one 24KB arena aliased per role.
__launch_bounds__(256)
__global__ void mega_kernel(const int* __restrict__ src, const int* __restrict__ dst,
                            int* __restrict__ gcursor, int2* __restrict__ pairs,
                            const float* __restrict__ x,
                            const float* __restrict__ wl,
                            const float* __restrict__ bl,
                            const float* __restrict__ br,
                            float* __restrict__ tmp,
                            const float* __restrict__ wp1, const float* __restrict__ bp1,
                            const float* __restrict__ wp2, const float* __restrict__ bp2,
                            float* __restrict__ wc4f, float* __restrict__ bc) {
  __shared__ __attribute__((aligned(16))) char smem[24576];
  int bid = blockIdx.x;

  if (bid < NH) {
    // ---- scatter2 role: LDS hist -> segment reserve -> LDS-cursor scatter --
    int* lh    = (int*)smem;               // [NB]
    int* lbase = lh + NB;                  // [NB]
    int* lcur  = lbase + NB;               // [NB]
    const int NQ = NE / 4;
    int t = bid * 256 + threadIdx.x;
    const int nt = NH * 256;
    for (int i = threadIdx.x; i < NB; i += 256) lh[i] = 0;
    __syncthreads();
    int4 dv[4], sv[4];
    bool pv[4];
    #pragma unroll
    for (int k = 0; k < 4; ++k) {
      int idx = t + k * nt;
      pv[k] = idx < NQ;
      if (pv[k]) {
        dv[k] = reinterpret_cast<const int4*>(dst)[idx];
        sv[k] = reinterpret_cast<const int4*>(src)[idx];
        atomicAdd(&lh[dv[k].x >> 9], 1);
        atomicAdd(&lh[dv[k].y >> 9], 1);
        atomicAdd(&lh[dv[k].z >> 9], 1);
        atomicAdd(&lh[dv[k].w >> 9], 1);
      }
    }
    __syncthreads();
    for (int i = threadIdx.x; i < NB; i += 256) {
      lcur[i] = 0;
      lbase[i] = lh[i] ? (i * CAP + atomicAdd(&gcursor[i], lh[i])) : 0;
    }
    __syncthreads();
    #pragma unroll
    for (int k = 0; k < 4; ++k) {
      if (pv[k]) {
        int b;
        b = dv[k].x >> 9; pairs[lbase[b] + atomicAdd(&lcur[b], 1)] = make_int2(sv[k].x, dv[k].x);
        b = dv[k].y >> 9; pairs[lbase[b] + atomicAdd(&lcur[b], 1)] = make_int2(sv[k].y, dv[k].y);
        b = dv[k].z >> 9; pairs[lbase[b] + atomicAdd(&lcur[b], 1)] = make_int2(sv[k].z, dv[k].z);
        b = dv[k].w >> 9; pairs[lbase[b] + atomicAdd(&lcur[b], 1)] = make_int2(sv[k].w, dv[k].w);
      }
    }
  } else if (bid < NH + NG1) {
    // ---- selfgemm role: tmp1 = x@w1l.T + (b1l+b1r) ----
    float4* wA4 = (float4*)smem;                         // [16*64] 16KB
    float (*sp)[8][DD] = (float(*)[8][DD])(smem + 16384); // [4][8][64] 8KB
    int vb = bid - NH;
    int tid = threadIdx.x;
    int j = tid & 63;
    int w = tid >> 6;                      // 0..3
    float* wAf = (float*)wA4;
    for (int i = tid; i < DD * DD; i += 256) {
      int jj = i >> 6, k = i & 63;         // wA4[k>>2][jj] elem (k&3) = wl[jj][k]
      wAf[(((k >> 2) * 64) + jj) * 4 + (k & 3)] = wl[i];
    }
    float bias = bl[j] + br[j];
    __syncthreads();
    const int ngrp = 3125;                 // 100000 / (4 waves * 8 nodes)
    for (int grp = vb; grp < ngrp; grp += NG1) {
      int n0 = (grp * 4 + w) * 8;
      const float4* xg = reinterpret_cast<const float4*>(&x[(size_t)n0 * DD]);
      float4* spv = reinterpret_cast<float4*>(&sp[w][0][0]);
      spv[j] = xg[j];
      spv[j + 64] = xg[j + 64];
      float acc[8];
      #pragma unroll
      for (int i = 0; i < 8; ++i) acc[i] = bias;
      #pragma unroll
      for (int q = 0; q < 16; ++q) {
        int kb = q * 4;
        float4 wq = wA4[q * 64 + j];
        #pragma unroll
        for (int i = 0; i < 8; ++i) {
          float4 sv = *(const float4*)&sp[w][i][kb];   // LDS broadcast
          float a = acc[i];
          a = fmaf(sv.x, wq.x, a);
          a = fmaf(sv.y, wq.y, a);
          a = fmaf(sv.z, wq.z, a);
          a = fmaf(sv.w, wq.w, a);
          acc[i] = a;
        }
      }
      #pragma unroll
      for (int i = 0; i < 8; ++i) tmp[(size_t)(n0 + i) * DD + j] = acc[i];
    }
  } else {
    // ---- combine role: wc = wp2@wp1 (packed [q][jp]), bc = wp2@bp1 + bp2 ---
    int t = threadIdx.x;
    for (int idx = t; idx < DD * DD; idx += 256) {
      int jp = idx >> 6, k = idx & 63;     // jp wave-uniform, k = lane
      float s = 0.f;
      #pragma unroll
      for (int m = 0; m < DD; ++m) s = fmaf(wp2[jp * DD + m], wp1[m * DD + k], s);
      wc4f[(((k >> 2) * 64) + jp) * 4 + (k & 3)] = s;
    }
    if (t < DD) {
      float s = bp2[t];
      #pragma unroll
      for (int m = 0; m < DD; ++m) s = fmaf(wp2[t * DD + m], bp1[m], s);
      bc[t] = s;
    }
  }
}

// ---------------- pass 2: per-bucket exact CSR (all LDS) --------------------
__launch_bounds__(256)
__global__ void csr_kernel(const int2* __restrict__ pairs, const int* __restrict__ gcursor,
                           int* __restrict__ deg, int* __restrict__ off,
                           int* __restrict__ adj) {
  __shared__ int lh[BKT];
  __shared__ int wsum[4];
  int b = blockIdx.x;
  int t = threadIdx.x;
  int rs = b * CAP, re = rs + gcursor[b];
  lh[2 * t] = 0;
  lh[2 * t + 1] = 0;
  __syncthreads();
  for (int i = rs + t; i < re; i += 256)
    atomicAdd(&lh[pairs[i].y - b * BKT], 1);
  __syncthreads();
  int lane = t & 63, w = t >> 6;
  int h0 = lh[2 * t], h1 = lh[2 * t + 1];
  int s = h0 + h1, incl = s;
  #pragma unroll
  for (int o = 1; o < 64; o <<= 1) {
    int u = __shfl_up(incl, o, 64);
    if (lane >= o) incl += u;
  }
  if (lane == 63) wsum[w] = incl;
  __syncthreads();
  int prefix = 0;
  for (int u = 0; u < w; ++u) prefix += wsum[u];
  int excl = prefix + incl - s;
  int n0 = b * BKT + 2 * t, n1 = n0 + 1;
  if (n0 < NN) { deg[n0] = h0; off[n0] = rs + excl; }
  if (n1 < NN) { deg[n1] = h1; off[n1] = rs + excl + h0; }
  lh[2 * t] = excl;
  lh[2 * t + 1] = excl + h0;
  __syncthreads();
  for (int i = rs + t; i < re; i += 256) {
    int2 e = pairs[i];
    int pos = atomicAdd(&lh[e.y - b * BKT], 1);
    adj[rs + pos] = e.x;
  }
}

// ---------------- gather-mean, 4 nodes/wave, float4 rows --------------------
__launch_bounds__(256)
__global__ void gather_kernel(const float* __restrict__ x,
                              const int* __restrict__ off,
                              const int* __restrict__ deg,
                              const int* __restrict__ adj,
                              float* __restrict__ prop) {
  const float4* X = reinterpret_cast<const float4*>(x);
  int wid = (blockIdx.x * 256 + threadIdx.x) >> 6;
  int nwaves = (gridDim.x * 256) >> 6;
  int lane = threadIdx.x & 63;
  int g = lane >> 4;
  int s = lane & 15;
  const int NQUAD = NN / 4;
  for (int q = wid; q < NQUAD; q += nwaves) {
    int n = q * 4 + g;
    int start = off[n];
    int d = deg[n];
    float4 a0 = {0,0,0,0}, a1 = {0,0,0,0}, a2 = {0,0,0,0}, a3 = {0,0,0,0};
    int t = 0;
    for (; t + 4 <= d; t += 4) {
      int i0 = adj[start + t + 0];
      int i1 = adj[start + t + 1];
      int i2 = adj[start + t + 2];
      int i3 = adj[start + t + 3];
      float4 v0 = X[i0 * 16 + s];
      float4 v1 = X[i1 * 16 + s];
      float4 v2 = X[i2 * 16 + s];
      float4 v3 = X[i3 * 16 + s];
      a0.x += v0.x; a0.y += v0.y; a0.z += v0.z; a0.w += v0.w;
      a1.x += v1.x; a1.y += v1.y; a1.z += v1.z; a1.w += v1.w;
      a2.x += v2.x; a2.y += v2.y; a2.z += v2.z; a2.w += v2.w;
      a3.x += v3.x; a3.y += v3.y; a3.z += v3.z; a3.w += v3.w;
    }
    if (t < d) {
      int dm = d - 1;
      int u1 = (t + 1 < d) ? t + 1 : dm;
      int u2 = (t + 2 < d) ? t + 2 : dm;
      int i0 = adj[start + t];
      int i1 = adj[start + u1];
      int i2 = adj[start + u2];
      float4 v0 = X[i0 * 16 + s];
      float4 v1 = X[i1 * 16 + s];
      float4 v2 = X[i2 * 16 + s];
      a0.x += v0.x; a0.y += v0.y; a0.z += v0.z; a0.w += v0.w;
      if (t + 1 < d) { a1.x += v1.x; a1.y += v1.y; a1.z += v1.z; a1.w += v1.w; }
      if (t + 2 < d) { a2.x += v2.x; a2.y += v2.y; a2.z += v2.z; a2.w += v2.w; }
    }
    float rc = 1.0f / fmaxf((float)d, 1.0f);
    float4 r;
    r.x = ((a0.x + a1.x) + (a2.x + a3.x)) * rc;
    r.y = ((a0.y + a1.y) + (a2.y + a3.y)) * rc;
    r.z = ((a0.z + a1.z) + (a2.z + a3.z)) * rc;
    r.w = ((a0.w + a1.w) + (a2.w + a3.w)) * rc;
    reinterpret_cast<float4*>(prop)[n * 16 + s] = r;
  }
}

// ---------------- light SAGE GEMM: out = relu(norm(tmp + prop@wr.T)) --------
__launch_bounds__(512, 4)
__global__ void gemm_light_kernel(float* __restrict__ out,
                                  const float* __restrict__ prop,
                                  const float* __restrict__ wr) {
  __shared__ float4 wrA4[16 * 64] __attribute__((aligned(16)));  // [q][j] 16KB
  __shared__ float pp[8][8][DD] __attribute__((aligned(16)));    // 16KB
  int tid = threadIdx.x;
  int j = tid & 63;
  int w = tid >> 6;
  float* wrf = (float*)wrA4;
  for (int i = tid; i < DD * DD; i += 512) {
    int jj = i >> 6, k = i & 63;
    wrf[(((k >> 2) * 64) + jj) * 4 + (k & 3)] = wr[i];
  }
  __syncthreads();

  const int ngrp = (NOCT + 7) / 8;   // 1563
  for (int grp = blockIdx.x; grp < ngrp; grp += gridDim.x) {
    int o = grp * 8 + w;
    if (o >= NOCT) continue;
    int n0 = o * 8;

    const float4* pg = reinterpret_cast<const float4*>(&prop[(size_t)n0 * DD]);
    float4* ppv = reinterpret_cast<float4*>(&pp[w][0][0]);
    ppv[j] = pg[j];
    ppv[j + 64] = pg[j + 64];

    float acc[8];
    #pragma unroll
    for (int i = 0; i < 8; ++i) acc[i] = out[(size_t)(n0 + i) * DD + j];  // tmp1

    #pragma unroll
    for (int q = 0; q < 16; ++q) {
      int kb = q * 4;
      float4 wq = wrA4[q * 64 + j];
      #pragma unroll
      for (int i = 0; i < 8; ++i) {
        float4 pv = *(const float4*)&pp[w][i][kb];   // LDS broadcast
        float a = acc[i];
        a = fmaf(pv.x, wq.x, a);
        a = fmaf(pv.y, wq.y, a);
        a = fmaf(pv.z, wq.z, a);
        a = fmaf(pv.w, wq.w, a);
        acc[i] = a;
      }
    }

    #pragma unroll
    for (int i = 0; i < 8; ++i) {
      float a = acc[i];
      float ss = a * a;
      #pragma unroll
      for (int o2 = 32; o2 > 0; o2 >>= 1) ss += __shfl_xor(ss, o2, 64);
      float ov = a / fmaxf(sqrtf(ss), 1e-12f);
      ov = fmaxf(ov, 0.0f);
      out[(size_t)(n0 + i) * DD + j] = ov;
    }
  }
}

// ---------------- fused layer-2 SAGE GEMM + post-MLP ------------------------
__launch_bounds__(512, 4)
__global__ void sage_post_kernel(const float* __restrict__ xin,
                                 const float* __restrict__ prop,
                                 const float* __restrict__ wl,
                                 const float* __restrict__ bl,
                                 const float* __restrict__ wr,
                                 const float* __restrict__ br,
                                 const float4* __restrict__ wc4,
                                 const float* __restrict__ bc,
                                 float* __restrict__ out) {
  __shared__ float4 wlA4[16 * 64] __attribute__((aligned(16)));  // 16KB
  __shared__ float4 wrA4[16 * 64] __attribute__((aligned(16)));  // 16KB
  __shared__ float sp[8][8][DD] __attribute__((aligned(16)));    // 16KB
  __shared__ float pp[8][8][DD] __attribute__((aligned(16)));    // 16KB
  int tid = threadIdx.x;
  int j = tid & 63;
  int w = tid >> 6;

  float* wlf = (float*)wlA4;
  float* wrf = (float*)wrA4;
  for (int i = tid; i < DD * DD; i += 512) {
    int jj = i >> 6, k = i & 63;
    wlf[(((k >> 2) * 64) + jj) * 4 + (k & 3)] = wl[i];
    wrf[(((k >> 2) * 64) + jj) * 4 + (k & 3)] = wr[i];
  }
  float bias = bl[j] + br[j];
  float bcv = bc[j];
  __syncthreads();

  const int ngrp = (NOCT + 7) / 8;
  for (int grp = blockIdx.x; grp < ngrp; grp += gridDim.x) {
    int o = grp * 8 + w;
    if (o >= NOCT) continue;
    int n0 = o * 8;

    const float4* xg = reinterpret_cast<const float4*>(&xin[(size_t)n0 * DD]);
    const float4* pg = reinterpret_cast<const float4*>(&prop[(size_t)n0 * DD]);
    float4* spv = reinterpret_cast<float4*>(&sp[w][0][0]);
    float4* ppv = reinterpret_cast<float4*>(&pp[w][0][0]);
    spv[j] = xg[j];
    spv[j + 64] = xg[j + 64];
    ppv[j] = pg[j];
    ppv[j + 64] = pg[j + 64];

    float acc[8];
    #pragma unroll
    for (int i = 0; i < 8; ++i) acc[i] = bias;

    #pragma unroll
    for (int q = 0; q < 16; ++q) {
      int kb = q * 4;
      float4 wlq = wlA4[q * 64 + j];
      float4 wrq = wrA4[q * 64 + j];
      #pragma unroll
      for (int i = 0; i < 8; ++i) {
        float4 sv = *(const float4*)&sp[w][i][kb];   // LDS broadcast
        float4 pv = *(const float4*)&pp[w][i][kb];   // LDS broadcast
        float a = acc[i];
        a = fmaf(sv.x, wlq.x, a);
        a = fmaf(sv.y, wlq.y, a);
        a = fmaf(sv.z, wlq.z, a);
        a = fmaf(sv.w, wlq.w, a);
        a = fmaf(pv.x, wrq.x, a);
        a = fmaf(pv.y, wrq.y, a);
        a = fmaf(pv.z, wrq.z, a);
        a = fmaf(pv.w, wrq.w, a);
        acc[i] = a;
      }
    }

    // L2 normalize + relu -> stage h into sp (wave-local reuse)
    #pragma unroll
    for (int i = 0; i < 8; ++i) {
      float a = acc[i];
      float ss = a * a;
      #pragma unroll
      for (int o2 = 32; o2 > 0; o2 >>= 1) ss += __shfl_xor(ss, o2, 64);
      float ov = a / fmaxf(sqrtf(ss), 1e-12f);
      ov = fmaxf(ov, 0.0f);
      sp[w][i][j] = ov;
    }

    // post phase: out = h @ wc.T + bc ; wc4 from global (coalesced, L1-hot)
    float acc2[8];
    #pragma unroll
    for (int i = 0; i < 8; ++i) acc2[i] = bcv;
    #pragma unroll
    for (int q = 0; q < 16; ++q) {
      int kb = q * 4;
      float4 wq = wc4[q * 64 + j];
      #pragma unroll
      for (int i = 0; i < 8; ++i) {
        float4 hv = *(const float4*)&sp[w][i][kb];   // LDS broadcast
        float a = acc2[i];
        a = fmaf(hv.x, wq.x, a);
        a = fmaf(hv.y, wq.y, a);
        a = fmaf(hv.z, wq.z, a);
        a = fmaf(hv.w, wq.w, a);
        acc2[i] = a;
      }
    }
    #pragma unroll
    for (int i = 0; i < 8; ++i) out[(size_t)(n0 + i) * DD + j] = acc2[i];
  }
}

extern "C" void kernel_launch(void* const* d_in, const int* in_sizes, int n_in,
                              void* d_out, int out_size, void* d_ws, size_t ws_size,
                              hipStream_t stream) {
  const float* x   = (const float*)d_in[0];
  const int*   ei  = (const int*)d_in[1];
  const float* w1l = (const float*)d_in[2];
  const float* b1l = (const float*)d_in[3];
  const float* w1r = (const float*)d_in[4];
  const float* b1r = (const float*)d_in[5];
  const float* w2l = (const float*)d_in[6];
  const float* b2l = (const float*)d_in[7];
  const float* w2r = (const float*)d_in[8];
  const float* b2r = (const float*)d_in[9];
  const float* wp1 = (const float*)d_in[10];
  const float* bp1 = (const float*)d_in[11];
  const float* wp2 = (const float*)d_in[12];
  const float* bp2 = (const float*)d_in[13];
  float* out = (float*)d_out;

  const int* src = ei;
  const int* dst = ei + NE;

  // ws (4B units): deg[102400] | off[102400] | aux[1024] | wc4[4096] | bc[1024]
  //               | adj[NB*CAP = 1764000] | prop[NN*DD]
  // pairs (int2[NB*CAP] = 14.1MB) aliases prop (dead before gather writes it).
  int* deg     = (int*)d_ws;
  int* off     = deg + 102400;
  int* aux     = off + 102400;
  int* gcursor = aux;
  float* wc4f  = (float*)(aux + 1024);
  float* bc    = wc4f + 4096;
  int* adj     = (int*)(bc + 1024);
  float* prop  = (float*)(adj + NB * CAP);
  int2* pairs  = (int2*)prop;

  // ---- scatter2 || selfgemm || combine (independent roles, one dispatch) ----
  hipMemsetAsync(gcursor, 0, NB * sizeof(int), stream);
  mega_kernel<<<NH + NG1 + 1, 256, 0, stream>>>(src, dst, gcursor, pairs,
                                                x, w1l, b1l, b1r, out,
                                                wp1, bp1, wp2, bp2, wc4f, bc);
  csr_kernel<<<NB, 256, 0, stream>>>(pairs, gcursor, deg, off, adj);

  // ---- layer 1: gather(x)->prop; out = relu(norm(tmp1 + prop@w1r.T)) ----
  gather_kernel<<<2048, 256, 0, stream>>>(x, off, deg, adj, prop);
  gemm_light_kernel<<<1024, 512, 0, stream>>>(out, prop, w1r);

  // ---- layer 2 + fused post: gather(out)->prop; sage+post -> out ----
  gather_kernel<<<2048, 256, 0, stream>>>(out, off, deg, adj, prop);
  sage_post_kernel<<<512, 512, 0, stream>>>(out, prop, w2l, b2l, w2r, b2r,
                                            (const float4*)wc4f, bc, out);
}